// Round 5
// baseline (186.662 us; speedup 1.0000x reference)
//
#include <hip/hip_runtime.h>
#include <math.h>

#define BB 8
#define VV 2
#define HH 1024
#define WW 1024
#define NPTS 131072
#define IMG (HH*WW)
#define FUSED (VV*BB*IMG)   // 16777216

#define NSOLVE (NPTS/256)      // 512 solve blocks
#define F4TOT  (FUSED/4)       // 4194304 float4 total copy

// dedup path: copy split K1/K2 (resolve must not overlap copy: it writes out[pix])
#define PER_CP   4                       // float4 per copy thread
#define NC_K1    2048                    // K1 copy blocks
#define COPY_K1  (NC_K1*256*PER_CP)      // 2097152 f4
#define NC_K2    2048                    // K2 copy blocks (rest)
// COPY_K1 + NC_K2*256*PER_CP == F4TOT   (2097152 + 2097152)

// fallback path: K1 copies everything
#define NC_FB    (F4TOT/(256*PER_CP))    // 4096 blocks

// native clang vector type: __builtin_nontemporal_store rejects HIP_vector_type
typedef float f32x4 __attribute__((ext_vector_type(4)));

// ---- workspace layout (bytes)
#define OFF_VAL  0u                          // float[2*NPTS] fused val (0 = invalid -> no write)
#define OFF_PIX  (8u*NPTS)                   // int[2*NPTS]
#define OFF_RED  (16u*NPTS)                  // int[NSOLVE*40] block slots: 16 near,16 far,8 has
#define OFF_WIN  (OFF_RED + 0x20000u)        // int[FUSED] = 64 MiB
#define WS_NEED  ((size_t)OFF_WIN + 4ull*(size_t)FUSED)

__device__ __forceinline__ int clampi(int v, int lo, int hi) {
    return v < lo ? lo : (v > hi ? hi : v);
}

// per-(b,v) prep (t = 0..15): P = (intr*rowscale) @ inv(E)[:3,:] -> sD[t*12..],
// e2 = inv(E)[2,:] -> sD[192 + t*4..].
// E is RIGID (R|t; 0 0 0 1) -> closed-form inverse [R^T | -R^T t]; static
// indexing only -> registers (runtime-pivot Gauss-Jordan went to scratch).
__device__ __forceinline__ void prep_one(int t, const float* __restrict__ intr,
                                         const float* __restrict__ extr, double* sD) {
    const float* E = extr + t * 16;
    double R[3][3], tr[3];
#pragma unroll
    for (int i = 0; i < 3; i++) {
#pragma unroll
        for (int j = 0; j < 3; j++) R[i][j] = (double)E[i * 4 + j];
        tr[i] = (double)E[i * 4 + 3];
    }
    double inv[3][4];   // rows 0..2 of inv(E); row 3 is (0,0,0,1)
#pragma unroll
    for (int i = 0; i < 3; i++) {
#pragma unroll
        for (int j = 0; j < 3; j++) inv[i][j] = R[j][i];
        inv[i][3] = -(R[0][i] * tr[0] + R[1][i] * tr[1] + R[2][i] * tr[2]);
    }
    const float* K = intr + t * 9;
    double rs[3] = {(double)WW, (double)HH, 1.0};
#pragma unroll
    for (int i = 0; i < 3; i++)
#pragma unroll
        for (int k = 0; k < 4; k++) {
            double s = 0.0;
#pragma unroll
            for (int j = 0; j < 3; j++) s += (double)K[i * 3 + j] * rs[i] * inv[j][k];
            sD[t * 12 + i * 4 + k] = s;
        }
#pragma unroll
    for (int k = 0; k < 4; k++) sD[192 + t * 4 + k] = inv[2][k];
}

__device__ __forceinline__ void copy_chunk(const f32x4* __restrict__ src,
                                           f32x4* __restrict__ dst,
                                           int base, int blk, int t) {
    int s = base + blk * (256 * PER_CP);
#pragma unroll
    for (int k = 0; k < PER_CP; k++) {
        int i = s + k * 256 + t;
        f32x4 v = src[i];
        // non-temporal: don't let the 64 MB out-copy evict disps from L2/LLC
        __builtin_nontemporal_store(v, &dst[i]);
    }
}

// K1: blocks [0,NSOLVE): per-point solve (z, valid, cost gather hidden under Jacobi,
//     val+pix store, own winner-cell clear, per-block near/far/has slots).
//     blocks >= NSOLVE: first half (dedup) / all (fallback) of the bulk copy.
template <int DEDUP>
__global__ __launch_bounds__(256) void mega_kernel(
        const f32x4* __restrict__ src, f32x4* __restrict__ dst,
        const float2* __restrict__ mk0, const float2* __restrict__ mk1,
        const int* __restrict__ mbids,
        const float* __restrict__ intr, const float* __restrict__ extr,
        const float* __restrict__ disps,
        float* __restrict__ out, char* __restrict__ ws) {
    int b = blockIdx.x, t = threadIdx.x;

    if (b >= NSOLVE) {                     // ---- copy role
        copy_chunk(src, dst, 0, b - NSOLVE, t);
        return;
    }

    // ---- solve role
    __shared__ double sD[256];             // 192 P doubles + 64 e2 doubles
    __shared__ int nearB[16], farB[16], hasB[8];
    if (t < 16) {
        prep_one(t, intr, extr, sD);
        nearB[t] = 0x7F800000;             // +inf bits
        farB[t]  = 0;                      // 0.0f bits
        if (t < 8) hasB[t] = 0;
    }
    __syncthreads();

    int n = b * 256 + t;
    float* valarr = (float*)(ws + OFF_VAL);
    int*   pixarr = (int*)(ws + OFF_PIX);
    int*   winner = (int*)(ws + OFF_WIN);

    int bid = mbids[n];
    float2 q0 = mk0[n], q1 = mk1[n];
    float xf[2] = {q0.x, q1.x};
    float yf[2] = {q0.y, q1.y};

    // M = A^T A  (mconf is a uniform positive scale of A -> no effect on eigvecs)
    double M[4][4];
#pragma unroll
    for (int i = 0; i < 4; i++)
#pragma unroll
        for (int j = 0; j < 4; j++) M[i][j] = 0.0;
#pragma unroll
    for (int v = 0; v < 2; v++) {
        const double* P = sD + (bid * VV + v) * 12;
        double xx = (double)xf[v], yy = (double)yf[v];
        double r0[4], r1[4];
#pragma unroll
        for (int j = 0; j < 4; j++) {
            r0[j] = xx * P[8 + j] - P[j];
            r1[j] = yy * P[8 + j] - P[4 + j];
        }
#pragma unroll
        for (int i = 0; i < 4; i++)
#pragma unroll
            for (int j = 0; j < 4; j++) M[i][j] += r0[i] * r0[j] + r1[i] * r1[j];
    }

    // cyclic Jacobi, f64 (verified: absmax 32)
    double Vm[4][4] = {{1, 0, 0, 0}, {0, 1, 0, 0}, {0, 0, 1, 0}, {0, 0, 0, 1}};
    for (int sweep = 0; sweep < 8; ++sweep) {
        double off = fabs(M[0][1]) + fabs(M[0][2]) + fabs(M[0][3]) +
                     fabs(M[1][2]) + fabs(M[1][3]) + fabs(M[2][3]);
        double dia = fabs(M[0][0]) + fabs(M[1][1]) + fabs(M[2][2]) + fabs(M[3][3]);
        if (off <= 1e-13 * dia) break;
#pragma unroll
        for (int p = 0; p < 3; p++) {
#pragma unroll
            for (int q = p + 1; q < 4; q++) {
                double apq = M[p][q];
                if (fabs(apq) < 1e-300) continue;
                double tau = (M[q][q] - M[p][p]) / (2.0 * apq);
                double rt  = sqrt(1.0 + tau * tau);
                double t_  = (tau >= 0.0) ? 1.0 / (tau + rt) : 1.0 / (tau - rt);
                double c = 1.0 / sqrt(1.0 + t_ * t_);
                double s = t_ * c;
#pragma unroll
                for (int k = 0; k < 4; k++) {
                    double mp = M[k][p], mq = M[k][q];
                    M[k][p] = c * mp - s * mq;
                    M[k][q] = s * mp + c * mq;
                }
#pragma unroll
                for (int k = 0; k < 4; k++) {
                    double mp = M[p][k], mq = M[q][k];
                    M[p][k] = c * mp - s * mq;
                    M[q][k] = s * mp + c * mq;
                }
#pragma unroll
                for (int k = 0; k < 4; k++) {
                    double vp = Vm[k][p], vq = Vm[k][q];
                    Vm[k][p] = c * vp - s * vq;
                    Vm[k][q] = s * vp + c * vq;
                }
            }
        }
    }
    int jmin = 0; double dmin = M[0][0];
    if (M[1][1] < dmin) { dmin = M[1][1]; jmin = 1; }
    if (M[2][2] < dmin) { dmin = M[2][2]; jmin = 2; }
    if (M[3][3] < dmin) { dmin = M[3][3]; jmin = 3; }

    double ev[4];
#pragma unroll
    for (int i = 0; i < 4; i++) {
        double a01 = (jmin == 0) ? Vm[i][0] : Vm[i][1];
        double a23 = (jmin == 2) ? Vm[i][2] : Vm[i][3];
        ev[i] = (jmin < 2) ? a01 : a23;
    }
    double iw  = 1.0 / ev[3];
    double pwx = ev[0] * iw, pwy = ev[1] * iw, pwz = ev[2] * iw;

    double z[2];
#pragma unroll
    for (int v = 0; v < 2; v++) {
        const double* e = sD + 192 + (bid * VV + v) * 4;
        z[v] = e[0] * pwx + e[1] * pwy + e[2] * pwz + e[3];
    }
    bool valid = (z[0] > 0.0) && (z[0] < 500.0) && (z[1] > 0.0) && (z[1] < 500.0);

    // block-local near/far/has via LDS (no global atomics, no init ordering)
    unsigned long long vb = __ballot(valid);
    int bidFirst = __shfl(bid, 0);
    int bidLast  = __shfl(bid, 63);
    if (bidFirst == bidLast) {
        if (vb != 0ULL) {
            float zn[2], zf[2];
#pragma unroll
            for (int v = 0; v < 2; v++) {
                zn[v] = valid ? (float)z[v] : INFINITY;
                zf[v] = valid ? (float)z[v] : -1.0f;
            }
#pragma unroll
            for (int off = 32; off > 0; off >>= 1) {
#pragma unroll
                for (int v = 0; v < 2; v++) {
                    zn[v] = fminf(zn[v], __shfl_down(zn[v], off));
                    zf[v] = fmaxf(zf[v], __shfl_down(zf[v], off));
                }
            }
            if ((t & 63) == 0) {
#pragma unroll
                for (int v = 0; v < 2; v++) {
                    atomicMin(&nearB[bid * VV + v], __float_as_int(zn[v]));
                    atomicMax(&farB[bid * VV + v],  __float_as_int(zf[v]));
                }
                atomicOr(&hasB[bid], 1);
            }
        }
    } else if (valid) {        // rare boundary wave
#pragma unroll
        for (int v = 0; v < 2; v++) {
            int fb = __float_as_int((float)z[v]);
            atomicMin(&nearB[bid * VV + v], fb);
            atomicMax(&farB[bid * VV + v],  fb);
        }
        atomicOr(&hasB[bid], 1);
    }

#pragma unroll
    for (int v = 0; v < 2; v++) {
        int xi = clampi((int)xf[v], 0, WW - 1);
        int yi = clampi((int)yf[v], 0, HH - 1);
        int pix = (v * BB + bid) * IMG + yi * WW + xi;
        float cost = disps[pix];               // scattered gather, hidden under Jacobi
        if (DEDUP) {
            winner[pix] = 0;                   // clear own winner cell (dup stores benign)
            // val==0 marks "winner writes nothing": invalid writes cost == the
            // copied value (no-op), so skipping the write is equivalent.
            valarr[2 * n + v] = valid ? (float)(0.5 * (1.0 / z[v]) + 0.5 * (double)cost)
                                      : 0.0f;
            pixarr[2 * n + v] = pix;
        } else {
            float val = valid ? (float)(0.5 * (1.0 / z[v]) + 0.5 * (double)cost) : cost;
            out[pix] = val;    // fallback: nondeterministic duplicate order
        }
    }

    __syncthreads();
    int* red = (int*)(ws + OFF_RED) + b * 40;
    if (t < 16) {
        red[t]      = nearB[t];
        red[16 + t] = farB[t];
        if (t < 8) red[32 + t] = hasB[t];
    }
}

// shared near/far/has reduce over the NSOLVE per-block slots (wave-parallel)
__device__ __forceinline__ void reduce_nearfar(const char* __restrict__ ws,
                                               float* __restrict__ out) {
    __shared__ int redLds[40];
    int t = threadIdx.x;
    const int* red = (const int*)(ws + OFF_RED);
    int w = t >> 6, lane = t & 63;
    for (int c = w; c < 40; c += 4) {          // 10 cells per wave
        int acc = (c < 16) ? 0x7F800000 : 0;
        for (int s = lane; s < NSOLVE; s += 64) {
            int vv = red[s * 40 + c];
            acc = (c < 16) ? min(acc, vv) : (c < 32 ? max(acc, vv) : (acc | vv));
        }
#pragma unroll
        for (int off = 32; off > 0; off >>= 1) {
            int o = __shfl_down(acc, off);
            acc = (c < 16) ? min(acc, o) : (c < 32 ? max(acc, o) : (acc | o));
        }
        if (lane == 0) redLds[c] = acc;
    }
    __syncthreads();
    if (t < 16) {
        int hv = redLds[32 + (t >> 1)];
        out[FUSED + t]               = hv ? __int_as_float(redLds[t])      : 0.0f;   // near
        out[FUSED + BB * VV + t]     = hv ? __int_as_float(redLds[16 + t]) : 500.0f; // far
        out[FUSED + 2 * BB * VV + t] = hv ? 1.0f : 0.0f;                             // flag
    }
}

// K2: vote (blocks < NSOLVE) overlapped with the second copy half (all blocks) +
//     near/far reduce on a copy-only block. Copy's streaming BW hides the
//     scattered-atomic latency of the vote. Kernel boundary ordered K1's clears.
__global__ __launch_bounds__(256) void vote_copy_kernel(
        const f32x4* __restrict__ src, f32x4* __restrict__ dst,
        char* __restrict__ ws, float* __restrict__ out) {
    int b = blockIdx.x, t = threadIdx.x;
    copy_chunk(src, dst, COPY_K1, b, t);
    if (b < NSOLVE) {
        int gid = b * 256 + t;
        const int2* pix2 = (const int2*)(ws + OFF_PIX);
        int* winner = (int*)(ws + OFF_WIN);
        int2 p = pix2[gid];
        atomicMax(winner + p.x, 2 * gid + 1);   // vote = id+1 (>0); max id == last-wins
        atomicMax(winner + p.y, 2 * gid + 2);
    } else if (b == NSOLVE) {
        reduce_nearfar(ws, out);
    }
}

// K3: winner writes its precomputed val. NO copy here: resolve writes arbitrary
// out[pix] and must not race the bulk copy (all copy completed by end of K2).
__global__ __launch_bounds__(256) void resolve_kernel(float* __restrict__ out,
                                                      const char* __restrict__ ws) {
    int gid = blockIdx.x * 256 + threadIdx.x;   // grid exactly NSOLVE
    const int2*   pix2 = (const int2*)(ws + OFF_PIX);
    const float2* val2 = (const float2*)(ws + OFF_VAL);
    const int*    winner = (const int*)(ws + OFF_WIN);
    int2 p = pix2[gid];
    float2 v = val2[gid];
    if (v.x > 0.0f && winner[p.x] == 2 * gid + 1) out[p.x] = v.x;
    if (v.y > 0.0f && winner[p.y] == 2 * gid + 2) out[p.y] = v.y;
}

// fallback-path reduce (1 block)
__global__ __launch_bounds__(256) void reduce_kernel(float* __restrict__ out,
                                                     const char* __restrict__ ws) {
    reduce_nearfar(ws, out);
}

extern "C" void kernel_launch(void* const* d_in, const int* in_sizes, int n_in,
                              void* d_out, int out_size, void* d_ws, size_t ws_size,
                              hipStream_t stream) {
    const float* mk0   = (const float*)d_in[0];
    const float* mk1   = (const float*)d_in[1];
    // d_in[2] = mconf: uniform positive scale of A, no effect on null vector -> unused
    const int*   mbids = (const int*)d_in[3];
    const float* intr  = (const float*)d_in[4];
    const float* extr  = (const float*)d_in[5];
    const float* disps = (const float*)d_in[6];
    float* out = (float*)d_out;
    char*  ws  = (char*)d_ws;

    bool dedup = (ws_size >= WS_NEED);

    if (dedup) {
        mega_kernel<1><<<dim3(NSOLVE + NC_K1), 256, 0, stream>>>(
            (const f32x4*)disps, (f32x4*)out, (const float2*)mk0, (const float2*)mk1,
            mbids, intr, extr, disps, out, ws);
        vote_copy_kernel<<<NC_K2, 256, 0, stream>>>(
            (const f32x4*)disps, (f32x4*)out, ws, out);
        resolve_kernel<<<NSOLVE, 256, 0, stream>>>(out, ws);
    } else {
        mega_kernel<0><<<dim3(NSOLVE + NC_FB), 256, 0, stream>>>(
            (const f32x4*)disps, (f32x4*)out, (const float2*)mk0, (const float2*)mk1,
            mbids, intr, extr, disps, out, ws);
        reduce_kernel<<<1, 256, 0, stream>>>(out, ws);
    }
}

// Round 6
// 184.394 us; speedup vs baseline: 1.0123x; 1.0123x over previous
//
#include <hip/hip_runtime.h>
#include <math.h>

#define BB 8
#define VV 2
#define HH 1024
#define WW 1024
#define NPTS 131072
#define IMG (HH*WW)
#define FUSED (VV*BB*IMG)   // 16777216

#define NSOLVE (NPTS/256)      // 512 solve blocks
#define F4TOT  (FUSED/4)       // 4194304 float4 total copy

// dedup path: copy split K1/K2 (resolve must not overlap copy: it writes out[pix])
#define PER_CP   4                       // float4 per copy thread
#define NC_K1    2048                    // K1 copy blocks
#define COPY_K1  (NC_K1*256*PER_CP)      // 2097152 f4
#define NC_K2    2048                    // K2 copy blocks (rest)
// COPY_K1 + NC_K2*256*PER_CP == F4TOT   (2097152 + 2097152)

// fallback path: K1 copies everything
#define NC_FB    (F4TOT/(256*PER_CP))    // 4096 blocks

// native clang vector type: __builtin_nontemporal_store rejects HIP_vector_type
typedef float f32x4 __attribute__((ext_vector_type(4)));

// ---- workspace layout (bytes)
#define OFF_VAL  0u                          // float[2*NPTS] fused val (0 = invalid -> no write)
#define OFF_PIX  (8u*NPTS)                   // int[2*NPTS]
#define OFF_RED  (16u*NPTS)                  // int[NSOLVE*40] block slots: 16 near,16 far,8 has
#define OFF_WIN  (OFF_RED + 0x20000u)        // int[FUSED] = 64 MiB
#define WS_NEED  ((size_t)OFF_WIN + 4ull*(size_t)FUSED)

__device__ __forceinline__ int clampi(int v, int lo, int hi) {
    return v < lo ? lo : (v > hi ? hi : v);
}

// per-(b,v) prep (t = 0..15): P = (intr*rowscale) @ inv(E)[:3,:] -> sD[t*12..],
// e2 = inv(E)[2,:] -> sD[192 + t*4..].
// E is RIGID (R|t; 0 0 0 1) -> closed-form inverse [R^T | -R^T t]; static
// indexing only -> registers.
__device__ __forceinline__ void prep_one(int t, const float* __restrict__ intr,
                                         const float* __restrict__ extr, double* sD) {
    const float* E = extr + t * 16;
    double R[3][3], tr[3];
#pragma unroll
    for (int i = 0; i < 3; i++) {
#pragma unroll
        for (int j = 0; j < 3; j++) R[i][j] = (double)E[i * 4 + j];
        tr[i] = (double)E[i * 4 + 3];
    }
    double inv[3][4];   // rows 0..2 of inv(E); row 3 is (0,0,0,1)
#pragma unroll
    for (int i = 0; i < 3; i++) {
#pragma unroll
        for (int j = 0; j < 3; j++) inv[i][j] = R[j][i];
        inv[i][3] = -(R[0][i] * tr[0] + R[1][i] * tr[1] + R[2][i] * tr[2]);
    }
    const float* K = intr + t * 9;
    double rs[3] = {(double)WW, (double)HH, 1.0};
#pragma unroll
    for (int i = 0; i < 3; i++)
#pragma unroll
        for (int k = 0; k < 4; k++) {
            double s = 0.0;
#pragma unroll
            for (int j = 0; j < 3; j++) s += (double)K[i * 3 + j] * rs[i] * inv[j][k];
            sD[t * 12 + i * 4 + k] = s;
        }
#pragma unroll
    for (int k = 0; k < 4; k++) sD[192 + t * 4 + k] = inv[2][k];
}

__device__ __forceinline__ void copy_chunk(const f32x4* __restrict__ src,
                                           f32x4* __restrict__ dst,
                                           int base, int blk, int t) {
    int s = base + blk * (256 * PER_CP);
#pragma unroll
    for (int k = 0; k < PER_CP; k++) {
        int i = s + k * 256 + t;
        f32x4 v = src[i];
        // non-temporal: don't let the 64 MB out-copy evict disps from L2/LLC
        __builtin_nontemporal_store(v, &dst[i]);
    }
}

// K1: blocks [0,NSOLVE): per-point solve; blocks >= NSOLVE: bulk copy share.
// Solve = f64 M-assembly -> f32 Jacobi (cheap div/sqrt, full-rate FMA) ->
// one f64 polish sweep on Md=V^T M V (quadratic convergence restores f64
// accuracy; output matches the previous all-f64 kernel to ~1e-9 rel).
template <int DEDUP>
__global__ __launch_bounds__(256) void mega_kernel(
        const f32x4* __restrict__ src, f32x4* __restrict__ dst,
        const float2* __restrict__ mk0, const float2* __restrict__ mk1,
        const int* __restrict__ mbids,
        const float* __restrict__ intr, const float* __restrict__ extr,
        const float* __restrict__ disps,
        float* __restrict__ out, char* __restrict__ ws) {
    int b = blockIdx.x, t = threadIdx.x;

    if (b >= NSOLVE) {                     // ---- copy role
        copy_chunk(src, dst, 0, b - NSOLVE, t);
        return;
    }

    // ---- solve role
    __shared__ double sD[256];             // 192 P doubles + 64 e2 doubles
    __shared__ int nearB[16], farB[16], hasB[8];

    // issue point loads before prep (independent of LDS)
    int n = b * 256 + t;
    int bid = mbids[n];
    float2 q0 = mk0[n], q1 = mk1[n];

    if (t < 16) {
        prep_one(t, intr, extr, sD);
        nearB[t] = 0x7F800000;             // +inf bits
        farB[t]  = 0;                      // 0.0f bits
        if (t < 8) hasB[t] = 0;
    }
    __syncthreads();

    float* valarr = (float*)(ws + OFF_VAL);
    int*   pixarr = (int*)(ws + OFF_PIX);
    int*   winner = (int*)(ws + OFF_WIN);

    float xf[2] = {q0.x, q1.x};
    float yf[2] = {q0.y, q1.y};

    // hoist scattered gather + winner clear ABOVE the eigensolve so the HBM
    // latency hides under compute
    int   pixv[2];
    float costv[2];
#pragma unroll
    for (int v = 0; v < 2; v++) {
        int xi = clampi((int)xf[v], 0, WW - 1);
        int yi = clampi((int)yf[v], 0, HH - 1);
        pixv[v] = (v * BB + bid) * IMG + yi * WW + xi;
        costv[v] = disps[pixv[v]];
        if (DEDUP) winner[pixv[v]] = 0;    // clear own cell (dup stores benign)
    }

    // M = A^T A in f64 (mconf is a uniform positive scale -> no effect on eigvecs)
    double M[4][4];
#pragma unroll
    for (int i = 0; i < 4; i++)
#pragma unroll
        for (int j = 0; j < 4; j++) M[i][j] = 0.0;
#pragma unroll
    for (int v = 0; v < 2; v++) {
        const double* P = sD + (bid * VV + v) * 12;
        double xx = (double)xf[v], yy = (double)yf[v];
        double r0[4], r1[4];
#pragma unroll
        for (int j = 0; j < 4; j++) {
            r0[j] = xx * P[8 + j] - P[j];
            r1[j] = yy * P[8 + j] - P[4 + j];
        }
#pragma unroll
        for (int i = 0; i < 4; i++)
#pragma unroll
            for (int j = 0; j < 4; j++) M[i][j] += r0[i] * r0[j] + r1[i] * r1[j];
    }

    // ---- f32 cyclic Jacobi on trace-normalized M
    double tr4 = M[0][0] + M[1][1] + M[2][2] + M[3][3];
    double itr = (tr4 > 0.0) ? 1.0 / tr4 : 1.0;
    float Mf[4][4], Vf[4][4] = {{1, 0, 0, 0}, {0, 1, 0, 0}, {0, 0, 1, 0}, {0, 0, 0, 1}};
#pragma unroll
    for (int i = 0; i < 4; i++)
#pragma unroll
        for (int j = 0; j < 4; j++) Mf[i][j] = (float)(M[i][j] * itr);

    for (int sweep = 0; sweep < 6; ++sweep) {
        float off = fabsf(Mf[0][1]) + fabsf(Mf[0][2]) + fabsf(Mf[0][3]) +
                    fabsf(Mf[1][2]) + fabsf(Mf[1][3]) + fabsf(Mf[2][3]);
        float dia = fabsf(Mf[0][0]) + fabsf(Mf[1][1]) + fabsf(Mf[2][2]) + fabsf(Mf[3][3]);
        if (off <= 1e-6f * dia) break;
#pragma unroll
        for (int p = 0; p < 3; p++) {
#pragma unroll
            for (int q = p + 1; q < 4; q++) {
                float apq = Mf[p][q];
                if (fabsf(apq) < 1e-30f) continue;
                float tau = (Mf[q][q] - Mf[p][p]) / (2.0f * apq);
                float rt  = sqrtf(1.0f + tau * tau);
                float t_  = (tau >= 0.0f) ? 1.0f / (tau + rt) : 1.0f / (tau - rt);
                float c = 1.0f / sqrtf(1.0f + t_ * t_);
                float s = t_ * c;
#pragma unroll
                for (int k = 0; k < 4; k++) {
                    float mp = Mf[k][p], mq = Mf[k][q];
                    Mf[k][p] = c * mp - s * mq;
                    Mf[k][q] = s * mp + c * mq;
                }
#pragma unroll
                for (int k = 0; k < 4; k++) {
                    float mp = Mf[p][k], mq = Mf[q][k];
                    Mf[p][k] = c * mp - s * mq;
                    Mf[q][k] = s * mp + c * mq;
                }
#pragma unroll
                for (int k = 0; k < 4; k++) {
                    float vp = Vf[k][p], vq = Vf[k][q];
                    Vf[k][p] = c * vp - s * vq;
                    Vf[k][q] = s * vp + c * vq;
                }
            }
        }
    }

    // ---- f64 polish: Md = V^T M V (nearly diagonal), one f64 cyclic sweep
    double Vd[4][4], T[4][4], Md[4][4];
#pragma unroll
    for (int i = 0; i < 4; i++)
#pragma unroll
        for (int j = 0; j < 4; j++) Vd[i][j] = (double)Vf[i][j];
#pragma unroll
    for (int i = 0; i < 4; i++)
#pragma unroll
        for (int j = 0; j < 4; j++) {
            double s = 0.0;
#pragma unroll
            for (int k = 0; k < 4; k++) s += M[i][k] * Vd[k][j];
            T[i][j] = s;
        }
#pragma unroll
    for (int i = 0; i < 4; i++)
#pragma unroll
        for (int j = 0; j < 4; j++) {
            double s = 0.0;
#pragma unroll
            for (int k = 0; k < 4; k++) s += Vd[k][i] * T[k][j];
            Md[i][j] = s;
        }
#pragma unroll
    for (int p = 0; p < 3; p++) {
#pragma unroll
        for (int q = p + 1; q < 4; q++) {
            double apq = Md[p][q];
            if (fabs(apq) < 1e-300) continue;
            double tau = (Md[q][q] - Md[p][p]) / (2.0 * apq);
            double rt  = sqrt(1.0 + tau * tau);
            double t_  = (tau >= 0.0) ? 1.0 / (tau + rt) : 1.0 / (tau - rt);
            double c = 1.0 / sqrt(1.0 + t_ * t_);
            double s = t_ * c;
#pragma unroll
            for (int k = 0; k < 4; k++) {
                double mp = Md[k][p], mq = Md[k][q];
                Md[k][p] = c * mp - s * mq;
                Md[k][q] = s * mp + c * mq;
            }
#pragma unroll
            for (int k = 0; k < 4; k++) {
                double mp = Md[p][k], mq = Md[q][k];
                Md[p][k] = c * mp - s * mq;
                Md[q][k] = s * mp + c * mq;
            }
#pragma unroll
            for (int k = 0; k < 4; k++) {
                double vp = Vd[k][p], vq = Vd[k][q];
                Vd[k][p] = c * vp - s * vq;
                Vd[k][q] = s * vp + c * vq;
            }
        }
    }

    int jmin = 0; double dmin = Md[0][0];
    if (Md[1][1] < dmin) { dmin = Md[1][1]; jmin = 1; }
    if (Md[2][2] < dmin) { dmin = Md[2][2]; jmin = 2; }
    if (Md[3][3] < dmin) { dmin = Md[3][3]; jmin = 3; }

    double ev[4];
#pragma unroll
    for (int i = 0; i < 4; i++) {
        double a01 = (jmin == 0) ? Vd[i][0] : Vd[i][1];
        double a23 = (jmin == 2) ? Vd[i][2] : Vd[i][3];
        ev[i] = (jmin < 2) ? a01 : a23;
    }
    double iw  = 1.0 / ev[3];
    double pwx = ev[0] * iw, pwy = ev[1] * iw, pwz = ev[2] * iw;

    double z[2];
#pragma unroll
    for (int v = 0; v < 2; v++) {
        const double* e = sD + 192 + (bid * VV + v) * 4;
        z[v] = e[0] * pwx + e[1] * pwy + e[2] * pwz + e[3];
    }
    bool valid = (z[0] > 0.0) && (z[0] < 500.0) && (z[1] > 0.0) && (z[1] < 500.0);

    // block-local near/far/has via LDS (no global atomics, no init ordering)
    unsigned long long vb = __ballot(valid);
    int bidFirst = __shfl(bid, 0);
    int bidLast  = __shfl(bid, 63);
    if (bidFirst == bidLast) {
        if (vb != 0ULL) {
            float zn[2], zf[2];
#pragma unroll
            for (int v = 0; v < 2; v++) {
                zn[v] = valid ? (float)z[v] : INFINITY;
                zf[v] = valid ? (float)z[v] : -1.0f;
            }
#pragma unroll
            for (int off = 32; off > 0; off >>= 1) {
#pragma unroll
                for (int v = 0; v < 2; v++) {
                    zn[v] = fminf(zn[v], __shfl_down(zn[v], off));
                    zf[v] = fmaxf(zf[v], __shfl_down(zf[v], off));
                }
            }
            if ((t & 63) == 0) {
#pragma unroll
                for (int v = 0; v < 2; v++) {
                    atomicMin(&nearB[bid * VV + v], __float_as_int(zn[v]));
                    atomicMax(&farB[bid * VV + v],  __float_as_int(zf[v]));
                }
                atomicOr(&hasB[bid], 1);
            }
        }
    } else if (valid) {        // rare boundary wave
#pragma unroll
        for (int v = 0; v < 2; v++) {
            int fb = __float_as_int((float)z[v]);
            atomicMin(&nearB[bid * VV + v], fb);
            atomicMax(&farB[bid * VV + v],  fb);
        }
        atomicOr(&hasB[bid], 1);
    }

#pragma unroll
    for (int v = 0; v < 2; v++) {
        int pix = pixv[v];
        float cost = costv[v];
        if (DEDUP) {
            // val==0 marks "winner writes nothing": invalid writes cost == the
            // copied value (no-op), so skipping the write is equivalent.
            valarr[2 * n + v] = valid ? (float)(0.5 * (1.0 / z[v]) + 0.5 * (double)cost)
                                      : 0.0f;
            pixarr[2 * n + v] = pix;
        } else {
            float val = valid ? (float)(0.5 * (1.0 / z[v]) + 0.5 * (double)cost) : cost;
            out[pix] = val;    // fallback: nondeterministic duplicate order
        }
    }

    __syncthreads();
    int* red = (int*)(ws + OFF_RED) + b * 40;
    if (t < 16) {
        red[t]      = nearB[t];
        red[16 + t] = farB[t];
        if (t < 8) red[32 + t] = hasB[t];
    }
}

// shared near/far/has reduce over the NSOLVE per-block slots (wave-parallel)
__device__ __forceinline__ void reduce_nearfar(const char* __restrict__ ws,
                                               float* __restrict__ out) {
    __shared__ int redLds[40];
    int t = threadIdx.x;
    const int* red = (const int*)(ws + OFF_RED);
    int w = t >> 6, lane = t & 63;
    for (int c = w; c < 40; c += 4) {          // 10 cells per wave
        int acc = (c < 16) ? 0x7F800000 : 0;
        for (int s = lane; s < NSOLVE; s += 64) {
            int vv = red[s * 40 + c];
            acc = (c < 16) ? min(acc, vv) : (c < 32 ? max(acc, vv) : (acc | vv));
        }
#pragma unroll
        for (int off = 32; off > 0; off >>= 1) {
            int o = __shfl_down(acc, off);
            acc = (c < 16) ? min(acc, o) : (c < 32 ? max(acc, o) : (acc | o));
        }
        if (lane == 0) redLds[c] = acc;
    }
    __syncthreads();
    if (t < 16) {
        int hv = redLds[32 + (t >> 1)];
        out[FUSED + t]               = hv ? __int_as_float(redLds[t])      : 0.0f;   // near
        out[FUSED + BB * VV + t]     = hv ? __int_as_float(redLds[16 + t]) : 500.0f; // far
        out[FUSED + 2 * BB * VV + t] = hv ? 1.0f : 0.0f;                             // flag
    }
}

// K2: vote (blocks < NSOLVE) overlapped with the second copy half (all blocks) +
//     near/far reduce on a copy-only block. Copy's streaming BW hides the
//     scattered-atomic latency of the vote. Kernel boundary ordered K1's clears.
__global__ __launch_bounds__(256) void vote_copy_kernel(
        const f32x4* __restrict__ src, f32x4* __restrict__ dst,
        char* __restrict__ ws, float* __restrict__ out) {
    int b = blockIdx.x, t = threadIdx.x;
    copy_chunk(src, dst, COPY_K1, b, t);
    if (b < NSOLVE) {
        int gid = b * 256 + t;
        const int2* pix2 = (const int2*)(ws + OFF_PIX);
        int* winner = (int*)(ws + OFF_WIN);
        int2 p = pix2[gid];
        atomicMax(winner + p.x, 2 * gid + 1);   // vote = id+1 (>0); max id == last-wins
        atomicMax(winner + p.y, 2 * gid + 2);
    } else if (b == NSOLVE) {
        reduce_nearfar(ws, out);
    }
}

// K3: winner writes its precomputed val. NO copy here: resolve writes arbitrary
// out[pix] and must not race the bulk copy (all copy completed by end of K2).
__global__ __launch_bounds__(256) void resolve_kernel(float* __restrict__ out,
                                                      const char* __restrict__ ws) {
    int gid = blockIdx.x * 256 + threadIdx.x;   // grid exactly NSOLVE
    const int2*   pix2 = (const int2*)(ws + OFF_PIX);
    const float2* val2 = (const float2*)(ws + OFF_VAL);
    const int*    winner = (const int*)(ws + OFF_WIN);
    int2 p = pix2[gid];
    float2 v = val2[gid];
    if (v.x > 0.0f && winner[p.x] == 2 * gid + 1) out[p.x] = v.x;
    if (v.y > 0.0f && winner[p.y] == 2 * gid + 2) out[p.y] = v.y;
}

// fallback-path reduce (1 block)
__global__ __launch_bounds__(256) void reduce_kernel(float* __restrict__ out,
                                                     const char* __restrict__ ws) {
    reduce_nearfar(ws, out);
}

extern "C" void kernel_launch(void* const* d_in, const int* in_sizes, int n_in,
                              void* d_out, int out_size, void* d_ws, size_t ws_size,
                              hipStream_t stream) {
    const float* mk0   = (const float*)d_in[0];
    const float* mk1   = (const float*)d_in[1];
    // d_in[2] = mconf: uniform positive scale of A, no effect on null vector -> unused
    const int*   mbids = (const int*)d_in[3];
    const float* intr  = (const float*)d_in[4];
    const float* extr  = (const float*)d_in[5];
    const float* disps = (const float*)d_in[6];
    float* out = (float*)d_out;
    char*  ws  = (char*)d_ws;

    bool dedup = (ws_size >= WS_NEED);

    if (dedup) {
        mega_kernel<1><<<dim3(NSOLVE + NC_K1), 256, 0, stream>>>(
            (const f32x4*)disps, (f32x4*)out, (const float2*)mk0, (const float2*)mk1,
            mbids, intr, extr, disps, out, ws);
        vote_copy_kernel<<<NC_K2, 256, 0, stream>>>(
            (const f32x4*)disps, (f32x4*)out, ws, out);
        resolve_kernel<<<NSOLVE, 256, 0, stream>>>(out, ws);
    } else {
        mega_kernel<0><<<dim3(NSOLVE + NC_FB), 256, 0, stream>>>(
            (const f32x4*)disps, (f32x4*)out, (const float2*)mk0, (const float2*)mk1,
            mbids, intr, extr, disps, out, ws);
        reduce_kernel<<<1, 256, 0, stream>>>(out, ws);
    }
}